// Round 11
// baseline (331.175 us; speedup 1.0000x reference)
//
#include <hip/hip_runtime.h>
#include <hip/hip_bf16.h>
#include <stdint.h>

#define TOKENS 8192
#define NOUT   4096
#define KIN    4096

#define BM 256
#define BN 256
#define BK 64
#define NT (KIN / BK)   // 64 K-tiles

typedef __attribute__((ext_vector_type(8))) short bf16x8;
typedef __attribute__((ext_vector_type(4))) float f32x4;

__device__ __forceinline__ uint32_t rotl32(uint32_t x, int r) {
  return (x << r) | (x >> (32 - r));
}

__device__ __forceinline__ uint16_t f2bf_rne(float f) {
  uint32_t u = __float_as_uint(f);
  u += 0x7FFFu + ((u >> 16) & 1u);
  return (uint16_t)(u >> 16);
}

// Threefry-2x32, 20 rounds — JAX PRNG core.
__device__ __forceinline__ void threefry2x32(uint32_t k0, uint32_t k1,
                                             uint32_t c0, uint32_t c1,
                                             uint32_t& o0, uint32_t& o1) {
  uint32_t ks2 = 0x1BD11BDAu ^ k0 ^ k1;
  uint32_t x0 = c0 + k0;
  uint32_t x1 = c1 + k1;
#define TFR(r) { x0 += x1; x1 = rotl32(x1, (r)); x1 ^= x0; }
  TFR(13) TFR(15) TFR(26) TFR(6)
  x0 += k1;  x1 += ks2 + 1u;
  TFR(17) TFR(29) TFR(16) TFR(24)
  x0 += ks2; x1 += k0 + 2u;
  TFR(13) TFR(15) TFR(26) TFR(6)
  x0 += k0;  x1 += k1 + 3u;
  TFR(17) TFR(29) TFR(16) TFR(24)
  x0 += k1;  x1 += ks2 + 4u;
  TFR(13) TFR(15) TFR(26) TFR(6)
  x0 += ks2; x1 += k0 + 5u;
#undef TFR
  o0 = x0; o1 = x1;
}

// Fused prep: blocks [0, 65536) hydrate W (partitionable threefry —
// VERIFIED round 3); blocks [65536, 81920) convert x fp32->bf16.
__global__ void prep_kernel(const float* __restrict__ x,
                            uint16_t* __restrict__ xb,
                            uint16_t* __restrict__ W,
                            const int* __restrict__ seed_ptr) {
  uint32_t b = blockIdx.x;
  if (b < 65536u) {
    uint32_t k1 = (uint32_t)(*seed_ptr);            // key = (0, seed)
    uint32_t j = b * 256u + threadIdx.x;            // 0 .. 2^24-1
    uint32_t o0, o1;
    threefry2x32(0u, k1, 0u, j, o0, o1);
    uint32_t bits = o0 ^ o1;
    const float scale = 0.03125f;
    const float mn    = -0.015625f;
    float f = __uint_as_float((bits >> 9) | 0x3F800000u) - 1.0f;
    float v = fmaxf(mn, f * scale + mn);
    W[j] = f2bf_rne(v);
  } else {
    uint32_t base = ((b - 65536u) * 256u + threadIdx.x) * 8u;
    f32x4 a = *(const f32x4*)(x + base);
    f32x4 c = *(const f32x4*)(x + base + 4);
    union { uint16_t u[8]; bf16x8 v; } r;
    r.u[0] = f2bf_rne(a[0]); r.u[1] = f2bf_rne(a[1]);
    r.u[2] = f2bf_rne(a[2]); r.u[3] = f2bf_rne(a[3]);
    r.u[4] = f2bf_rne(c[0]); r.u[5] = f2bf_rne(c[1]);
    r.u[6] = f2bf_rne(c[2]); r.u[7] = f2bf_rne(c[3]);
    *(bf16x8*)(xb + base) = r.v;
  }
}

// ---------------------------------------------------------------------------
// 256x256 / BK=64 / 8-wave / 8-phase / 16x16x32, phase-ahead operand
// prefetch. Round 11 change vs round 10 (single variable): P4 issues the
// next tile's af0/bv0 ds_reads BEFORE its MFMA cluster (right after the
// VMW+barrier, where the data is proven resident), not after — so the
// reads land under the 16-MFMA shadow and P1's LKW(4) is ~free.
//
// Ledger (r9/r10-verified):
//   P1: MFMA(0,0) af0,bv0 | read bv1 (4)   | stage A1(kt+1)->buf^1 | LKW(4)
//   P2: MFMA(0,1) af0,bv1 | read af1 (8)   | stage A0(kt+2)->buf   | LKW(8)
//   P3: MFMA(1,0) af1,bv0 | no reads       | stage B0(kt+2)->buf   | LKW(0)
//   P4: stage B1(kt+2)->buf | VMW(6) | barrier | read af0,bv0 of next
//       tile from buf^1 (12) | MFMA(1,1) af1,bv1 | barrier
// RAW @P4 VMW(6): 6 newest = kt+2's A0,B0,B1 -> A1(kt+1) and older landed.
// WAR: every stage lands >= 1 drained-lgkm + barrier after last read.
// Register WAR: P4's MFMA uses af1/bv1; new reads fill dead af0/bv0.
// Addressing diet (r10): 4 stage pointers; 8 precomputed ds_read base
// offsets (s1 = s0 ^ 64 — exact, bit6 of all additive immediates is 0);
// all reads = base + compile-time immediate.
// LDS swizzle: linear gload_lds dest + inverse-swizzled global source;
// reads XOR byte ((row&7)<<4). Rounds 5-7/10: 0 bank conflicts.
// ---------------------------------------------------------------------------
__global__ __launch_bounds__(512, 2)
void gemm_bias_kernel(const uint16_t* __restrict__ A,   // x  bf16 [TOKENS][KIN]
                      const uint16_t* __restrict__ B,   // W  bf16 [NOUT][KIN]
                      const float* __restrict__ bias,
                      float* __restrict__ C) {
  __shared__ uint16_t smem[2][2][16384];   // [buf][A=0/B=1][32KB] = 128 KiB

  const int nwgn = NOUT / BN;                 // 16
  const int nwg  = (TOKENS / BM) * nwgn;      // 512
  int bid = blockIdx.x;
  int cpx = nwg >> 3;
  int swzb = (bid & 7) * cpx + (bid >> 3);    // bijective XCD swizzle
  const int tm = (swzb / nwgn) * BM;
  const int tn = (swzb % nwgn) * BN;

  const int t    = threadIdx.x;
  const int lane = t & 63;
  const int wid  = t >> 6;
  const int wm   = wid >> 2;
  const int wn   = wid & 3;
  const int fr   = lane & 15;
  const int fq   = lane >> 4;
  const int swzRd = (lane & 7) << 4;
  const int lsw   = ((lane & 7) ^ (lane >> 3)) << 4;

  // stage source pointers (per-thread); per call: + (ktByte + small const)
  const char* pA0 = (const char*)(A + (size_t)(tm + wid * 16 + (lane >> 3)) * KIN) + lsw;
  const char* pB0 = (const char*)(B + (size_t)(tn + wid * 16 + (lane >> 3)) * KIN) + lsw;
  const char* pA1 = pA0 + (size_t)128 * KIN * 2;   // h=1: +128 rows
  const char* pB1 = pB0 + (size_t)128 * KIN * 2;

  char* const smemB = (char*)&smem[0][0][0];
  char* const dstB  = smemB + wid * 2048 + lane * 16;

  // ds_read base byte-offsets (relative to smemB)
  const int rA00 = (wm * 64 + fr) * 128 + ((fq << 4) ^ swzRd);  // A buf0 s0
  const int rA01 = rA00 ^ 64;                                    // A buf0 s1
  const int rA10 = rA00 + 65536;                                 // A buf1 s0
  const int rA11 = rA10 ^ 64;
  const int rB00 = 32768 + (wn * 32 + fr) * 128 + ((fq << 4) ^ swzRd);
  const int rB01 = rB00 ^ 64;
  const int rB10 = rB00 + 65536;
  const int rB11 = rB10 ^ 64;

  f32x4 acc[8][4] = {};
  bf16x8 af0[2][4], af1[2][4], bv0[2][2], bv1[2][2];

  auto stage2 = [&](const char* src, char* dst) {
    __builtin_amdgcn_global_load_lds(
        (const __attribute__((address_space(1))) void*)src,
        (__attribute__((address_space(3))) void*)dst, 16, 0, 0);
    __builtin_amdgcn_global_load_lds(
        (const __attribute__((address_space(1))) void*)(src + (size_t)8 * KIN * 2),
        (__attribute__((address_space(3))) void*)(dst + 1024), 16, 0, 0);
  };

#define VMW(N) asm volatile("s_waitcnt vmcnt(" #N ")" ::: "memory")
#define LKW(N) asm volatile("s_waitcnt lgkmcnt(" #N ")" ::: "memory")
#define SB0    __builtin_amdgcn_sched_barrier(0)
#define PRI(p) __builtin_amdgcn_s_setprio(p)

#define RD_A(S0, S1, AF, MH)                                                   \
    _Pragma("unroll")                                                          \
    for (int i_ = 0; i_ < 4; ++i_) {                                           \
      AF[0][i_] = *(const bf16x8*)(smemB + (S0) + (MH) * 16384 + i_ * 2048);   \
      AF[1][i_] = *(const bf16x8*)(smemB + (S1) + (MH) * 16384 + i_ * 2048);   \
    }

#define RD_B(S0, S1, BV, NH)                                                   \
    _Pragma("unroll")                                                          \
    for (int j_ = 0; j_ < 2; ++j_) {                                           \
      BV[0][j_] = *(const bf16x8*)(smemB + (S0) + (NH) * 16384 + j_ * 2048);   \
      BV[1][j_] = *(const bf16x8*)(smemB + (S1) + (NH) * 16384 + j_ * 2048);   \
    }

#define MF16(MH, NH, AF, BV)                                                   \
    _Pragma("unroll")                                                          \
    for (int s_ = 0; s_ < 2; ++s_)                                             \
      _Pragma("unroll")                                                        \
      for (int i_ = 0; i_ < 4; ++i_)                                           \
        _Pragma("unroll")                                                      \
        for (int j_ = 0; j_ < 2; ++j_)                                         \
          acc[(MH) * 4 + i_][(NH) * 2 + j_] =                                  \
              __builtin_amdgcn_mfma_f32_16x16x32_bf16(                         \
                  AF[s_][i_], BV[s_][j_], acc[(MH) * 4 + i_][(NH) * 2 + j_],   \
                  0, 0, 0);

  // MODE: 0 = steady; 1 = kt62 (stage only A1(63), VMW(0)@P4);
  //       2 = kt63 (no stages, no vm waits, no next-tile reads).
#define KTILE(BUF, KTB, MODE)                                                  \
  {                                                                            \
    /* P1 */                                                                   \
    RD_B((BUF) ? rB10 : rB00, (BUF) ? rB11 : rB01, bv1, 1)                     \
    if ((MODE) <= 1) stage2(pA1 + (KTB) + 128,                                 \
                            dstB + ((BUF) ^ 1) * 65536 + 16384);               \
    __builtin_amdgcn_s_barrier();                                              \
    LKW(4); SB0; PRI(1); MF16(0, 0, af0, bv0) PRI(0);                          \
    __builtin_amdgcn_s_barrier();                                              \
    /* P2 */                                                                   \
    RD_A((BUF) ? rA10 : rA00, (BUF) ? rA11 : rA01, af1, 1)                     \
    if ((MODE) == 0) stage2(pA0 + (KTB) + 256, dstB + (BUF) * 65536);          \
    __builtin_amdgcn_s_barrier();                                              \
    LKW(8); SB0; PRI(1); MF16(0, 1, af0, bv1) PRI(0);                          \
    __builtin_amdgcn_s_barrier();                                              \
    /* P3 */                                                                   \
    if ((MODE) == 0) stage2(pB0 + (KTB) + 256, dstB + (BUF) * 65536 + 32768);  \
    __builtin_amdgcn_s_barrier();                                              \
    LKW(0); SB0; PRI(1); MF16(1, 0, af1, bv0) PRI(0);                          \
    __builtin_amdgcn_s_barrier();                                              \
    /* P4: stage B1(kt+2) | VMW | barrier | READS FIRST (land under MFMA   */ \
    /* shadow; no reg dependence with MFMA(1,1)) | MFMA | barrier          */ \
    if ((MODE) == 0) stage2(pB1 + (KTB) + 256,                                 \
                            dstB + (BUF) * 65536 + 32768 + 16384);             \
    if ((MODE) == 0) { VMW(6); } else if ((MODE) == 1) { VMW(0); }             \
    __builtin_amdgcn_s_barrier();                                              \
    if ((MODE) <= 1) {                                                         \
      RD_A((BUF) ? rA00 : rA10, (BUF) ? rA01 : rA11, af0, 0)                   \
      RD_B((BUF) ? rB00 : rB10, (BUF) ? rB01 : rB11, bv0, 0)                   \
    }                                                                          \
    SB0;                                                                       \
    PRI(1); MF16(1, 1, af1, bv1) PRI(0);                                       \
    __builtin_amdgcn_s_barrier();                                              \
  }

  // Prologue: stage kt0 fully -> buf0; land; barrier; pre-read af0/bv0(kt0);
  // stage kt1's A0,B0,B1 -> buf1 (A1(kt1) arrives at tile 0's P1 slot).
  stage2(pA0, dstB);                       // A0 kt0 buf0
  stage2(pB0, dstB + 32768);               // B0 kt0 buf0
  stage2(pB1, dstB + 32768 + 16384);       // B1 kt0 buf0
  stage2(pA1, dstB + 16384);               // A1 kt0 buf0
  VMW(0);
  __builtin_amdgcn_s_barrier();
  RD_A(rA00, rA01, af0, 0)
  RD_B(rB00, rB01, bv0, 0)
  stage2(pA0 + 128, dstB + 65536);                   // A0 kt1 buf1
  stage2(pB0 + 128, dstB + 65536 + 32768);           // B0 kt1 buf1
  stage2(pB1 + 128, dstB + 65536 + 32768 + 16384);   // B1 kt1 buf1

  for (int ktB = 0; ktB < (NT - 2) * 128; ktB += 256) {
    KTILE(0, ktB, 0)
    KTILE(1, ktB + 128, 0)
  }
  KTILE(0, 62 * 128, 1)
  KTILE(1, 63 * 128, 2)

#undef KTILE
#undef MF16
#undef RD_B
#undef RD_A
#undef PRI
#undef SB0
#undef LKW
#undef VMW

  // Epilogue: D row = fq*4 + rr, col = fr (m89/m91-verified), fused bias.
#pragma unroll
  for (int nj = 0; nj < 4; ++nj) {
    const int nh = nj >> 1, j = nj & 1;
    const int col = tn + wn * 32 + nh * 128 + j * 16 + fr;
    const float bvs = bias[col];
#pragma unroll
    for (int mi = 0; mi < 8; ++mi) {
      const int mh = mi >> 2, i = mi & 3;
      const int row0 = tm + wm * 64 + mh * 128 + i * 16 + fq * 4;
#pragma unroll
      for (int rr = 0; rr < 4; ++rr)
        C[(size_t)(row0 + rr) * NOUT + col] = acc[mi][nj][rr] + bvs;
    }
  }
}

extern "C" void kernel_launch(void* const* d_in, const int* in_sizes, int n_in,
                              void* d_out, int out_size, void* d_ws, size_t ws_size,
                              hipStream_t stream) {
  const float* x    = (const float*)d_in[0];   // [8192][4096] fp32
  const float* bias = (const float*)d_in[1];   // [4096] fp32
  const int*   seed = (const int*)d_in[2];     // [1] int
  float* y = (float*)d_out;                    // [8192][4096] fp32

  // workspace: W bf16 (32 MB) | x bf16 (64 MB) — 96 MB, proven available
  uint16_t* Wb = (uint16_t*)d_ws;
  uint16_t* Xb = Wb + (size_t)NOUT * KIN;

  prep_kernel<<<65536 + 16384, 256, 0, stream>>>(x, Xb, Wb, seed);

  const int grid = (TOKENS / BM) * (NOUT / BN);   // 512
  gemm_bias_kernel<<<grid, 512, 0, stream>>>(Xb, Wb, bias, y);
}

// Round 12
// 272.985 us; speedup vs baseline: 1.2132x; 1.2132x over previous
//
#include <hip/hip_runtime.h>
#include <hip/hip_bf16.h>
#include <stdint.h>

#define TOKENS 8192
#define NOUT   4096
#define KIN    4096

#define BM 256
#define BN 256
#define BK 64
#define NT (KIN / BK)   // 64 K-tiles

typedef __attribute__((ext_vector_type(8))) short bf16x8;
typedef __attribute__((ext_vector_type(4))) float f32x4;

__device__ __forceinline__ uint32_t rotl32(uint32_t x, int r) {
  return (x << r) | (x >> (32 - r));
}

__device__ __forceinline__ uint16_t f2bf_rne(float f) {
  uint32_t u = __float_as_uint(f);
  u += 0x7FFFu + ((u >> 16) & 1u);
  return (uint16_t)(u >> 16);
}

// Threefry-2x32, 20 rounds — JAX PRNG core.
__device__ __forceinline__ void threefry2x32(uint32_t k0, uint32_t k1,
                                             uint32_t c0, uint32_t c1,
                                             uint32_t& o0, uint32_t& o1) {
  uint32_t ks2 = 0x1BD11BDAu ^ k0 ^ k1;
  uint32_t x0 = c0 + k0;
  uint32_t x1 = c1 + k1;
#define TFR(r) { x0 += x1; x1 = rotl32(x1, (r)); x1 ^= x0; }
  TFR(13) TFR(15) TFR(26) TFR(6)
  x0 += k1;  x1 += ks2 + 1u;
  TFR(17) TFR(29) TFR(16) TFR(24)
  x0 += ks2; x1 += k0 + 2u;
  TFR(13) TFR(15) TFR(26) TFR(6)
  x0 += k0;  x1 += k1 + 3u;
  TFR(17) TFR(29) TFR(16) TFR(24)
  x0 += k1;  x1 += ks2 + 4u;
  TFR(13) TFR(15) TFR(26) TFR(6)
  x0 += ks2; x1 += k0 + 5u;
#undef TFR
  o0 = x0; o1 = x1;
}

// Fused prep: blocks [0, 65536) hydrate W (partitionable threefry —
// VERIFIED round 3); blocks [65536, 81920) convert x fp32->bf16.
__global__ void prep_kernel(const float* __restrict__ x,
                            uint16_t* __restrict__ xb,
                            uint16_t* __restrict__ W,
                            const int* __restrict__ seed_ptr) {
  uint32_t b = blockIdx.x;
  if (b < 65536u) {
    uint32_t k1 = (uint32_t)(*seed_ptr);            // key = (0, seed)
    uint32_t j = b * 256u + threadIdx.x;            // 0 .. 2^24-1
    uint32_t o0, o1;
    threefry2x32(0u, k1, 0u, j, o0, o1);
    uint32_t bits = o0 ^ o1;
    const float scale = 0.03125f;
    const float mn    = -0.015625f;
    float f = __uint_as_float((bits >> 9) | 0x3F800000u) - 1.0f;
    float v = fmaxf(mn, f * scale + mn);
    W[j] = f2bf_rne(v);
  } else {
    uint32_t base = ((b - 65536u) * 256u + threadIdx.x) * 8u;
    f32x4 a = *(const f32x4*)(x + base);
    f32x4 c = *(const f32x4*)(x + base + 4);
    union { uint16_t u[8]; bf16x8 v; } r;
    r.u[0] = f2bf_rne(a[0]); r.u[1] = f2bf_rne(a[1]);
    r.u[2] = f2bf_rne(a[2]); r.u[3] = f2bf_rne(a[3]);
    r.u[4] = f2bf_rne(c[0]); r.u[5] = f2bf_rne(c[1]);
    r.u[6] = f2bf_rne(c[2]); r.u[7] = f2bf_rne(c[3]);
    *(bf16x8*)(xb + base) = r.v;
  }
}

// ---------------------------------------------------------------------------
// 256x256 / BK=64 / 8-wave / 16x16x32, SINGLE-BARRIER phases (4 barriers per
// K-tile, was 8). Round 12 change vs r7: drop each phase's trailing barrier
// so waves skew by up to one phase — a fast wave's ds_reads drain while slow
// waves' MFMAs run, overlapping LDS-port and MFMA-pipe occupancy that the
// two-barrier lockstep serialized (r7 measured 4517 cyc/K-tile vs
// max(MFMA 2483, LDS 2816) ideal).
//
// Phase = { reads; stage; s_barrier; lgkm(0); MFMA }.
// WAR proof with single barriers: a wave ARRIVES at barrier_p only after
// completing MFMA_{p-1}, which required its lgkm(0) — so its phase-(p-1)
// reads are COMPLETE. Any stage issued after passing barrier_p is therefore
// safe against reads from phases <= p-1  =>  stage slots need 2-phase lag:
//   P1: reads A0->af, B0->bv0 (12) | stage A1(kt+1)->buf^1 | MFMA(0,0)
//   P2: reads B1->bv1 (4)          |                       | MFMA(0,1)
//   P3: reads A1->af (8)           | stage A0+B0(kt+2)->buf| MFMA(1,1)
//   P4: no reads                   | stage B1(kt+2)->buf, VMW(6) | MFMA(1,0)
//   (A0 read P1 / staged P3: 2-phase lag OK; B0 read P1 / staged P3 OK;
//    B1 read P2 / staged P4 OK; A1 read P3 / staged next-P1 OK.)
// RAW @P4 VMW(6): per-tile loads = P1:2, P3:4, P4:2; the 6 newest at the
// wait are P3+P4's (kt+2) -> everything through A1(kt+1) landed; barrier_P4
// publishes all waves' stages (each passed its own VMW). kt+1 resident
// before its P1 reads. Tail: kt62 stages only A1(63), VMW(0)@P4; kt63 none.
// Registers: af(32)+bv0(16)+bv1(16) = 64 operand VGPRs — r7 footprint,
// no spill. LDS swizzle: linear gload_lds dest + inverse-swizzled global
// source; reads XOR byte ((row&7)<<4). Rounds 5-7: 0 bank conflicts.
// ---------------------------------------------------------------------------
__global__ __launch_bounds__(512, 2)
void gemm_bias_kernel(const uint16_t* __restrict__ A,   // x  bf16 [TOKENS][KIN]
                      const uint16_t* __restrict__ B,   // W  bf16 [NOUT][KIN]
                      const float* __restrict__ bias,
                      float* __restrict__ C) {
  __shared__ uint16_t smem[2][2][16384];   // [buf][A=0/B=1][32KB] = 128 KiB

  const int nwgn = NOUT / BN;                 // 16
  const int nwg  = (TOKENS / BM) * nwgn;      // 512 (divisible by 8)
  int bid = blockIdx.x;
  int cpx = nwg >> 3;
  int swzb = (bid & 7) * cpx + (bid >> 3);    // bijective XCD swizzle
  int tm = (swzb / nwgn) * BM;
  int tn = (swzb % nwgn) * BN;

  const int t    = threadIdx.x;
  const int lane = t & 63;
  const int wid  = t >> 6;       // 0..7
  const int wm   = wid >> 2;     // 0..1
  const int wn   = wid & 3;      // 0..3
  const int fr   = lane & 15;
  const int fq   = lane >> 4;

  const int swzRd = (lane & 7) << 4;                    // frag-read byte XOR
  const int lsw   = ((lane & 7) ^ (lane >> 3)) << 4;    // stage src byte offset

  f32x4 acc[8][4] = {};

  auto stageHalf = [&](int mat, int h, int kt, int buf) {
    const uint16_t* g = mat ? B : A;
    const int rb = (mat ? tn : tm) + h * 128 + wid * 16 + (lane >> 3);
    const char* src = (const char*)(g + (size_t)rb * KIN) + kt * 128 + lsw;
    char* dst = (char*)&smem[buf][mat][0] + h * 16384 + wid * 2048 + lane * 16;
#pragma unroll
    for (int q = 0; q < 2; ++q) {
      __builtin_amdgcn_global_load_lds(
          (const __attribute__((address_space(1))) void*)(src + (size_t)q * 8 * KIN * 2),
          (__attribute__((address_space(3))) void*)(dst + q * 1024),
          16, 0, 0);
    }
  };

#define VMW(N) asm volatile("s_waitcnt vmcnt(" #N ")" ::: "memory")
#define LKW(N) asm volatile("s_waitcnt lgkmcnt(" #N ")" ::: "memory")
#define SB0    __builtin_amdgcn_sched_barrier(0)
#define PRI(p) __builtin_amdgcn_s_setprio(p)

#define RD_A(BUFI, MH)                                                         \
    _Pragma("unroll")                                                          \
    for (int s_ = 0; s_ < 2; ++s_) {                                           \
      const int kb_ = (s_ << 6) | (fq << 4);                                   \
      _Pragma("unroll")                                                        \
      for (int i_ = 0; i_ < 4; ++i_)                                           \
        af[s_][i_] = *(const bf16x8*)((const char*)&smem[BUFI][0][0] +         \
            (wm * 64 + (MH) * 128 + i_ * 16 + fr) * 128 + (kb_ ^ swzRd));      \
    }

#define RD_B(BUFI, BV, NH)                                                     \
    _Pragma("unroll")                                                          \
    for (int s_ = 0; s_ < 2; ++s_) {                                           \
      const int kb_ = (s_ << 6) | (fq << 4);                                   \
      _Pragma("unroll")                                                        \
      for (int j_ = 0; j_ < 2; ++j_)                                           \
        BV[s_][j_] = *(const bf16x8*)((const char*)&smem[BUFI][1][0] +         \
            (wn * 32 + (NH) * 128 + j_ * 16 + fr) * 128 + (kb_ ^ swzRd));      \
    }

#define MF16(MH, NH, BV)                                                       \
    _Pragma("unroll")                                                          \
    for (int s_ = 0; s_ < 2; ++s_)                                             \
      _Pragma("unroll")                                                        \
      for (int i_ = 0; i_ < 4; ++i_)                                           \
        _Pragma("unroll")                                                      \
        for (int j_ = 0; j_ < 2; ++j_)                                         \
          acc[(MH) * 4 + i_][(NH) * 2 + j_] =                                  \
              __builtin_amdgcn_mfma_f32_16x16x32_bf16(                         \
                  af[s_][i_], BV[s_][j_], acc[(MH) * 4 + i_][(NH) * 2 + j_],   \
                  0, 0, 0);

  // MODE: 0 = steady; 1 = kt62 (stage only A1(63)@P1, VMW(0)@P4);
  //       2 = kt63 (no stages, no vm waits).
#define KTILE(BUF, KT, MODE)                                                   \
  {                                                                            \
    /* P1: reads A0,B0 | stage A1(kt+1)->buf^1 | barrier | MFMA(0,0) */        \
    RD_A(BUF, 0) RD_B(BUF, bv0, 0)                                             \
    if ((MODE) <= 1) stageHalf(0, 1, (KT) + 1, (BUF) ^ 1);                     \
    __builtin_amdgcn_s_barrier();                                              \
    LKW(0); SB0; PRI(1); MF16(0, 0, bv0) PRI(0);                               \
    /* P2: reads B1 | barrier | MFMA(0,1) */                                   \
    RD_B(BUF, bv1, 1)                                                          \
    __builtin_amdgcn_s_barrier();                                              \
    LKW(0); SB0; PRI(1); MF16(0, 1, bv1) PRI(0);                               \
    /* P3: reads A1 | stage A0+B0(kt+2)->buf | barrier | MFMA(1,1) */          \
    RD_A(BUF, 1)                                                               \
    if ((MODE) == 0) { stageHalf(0, 0, (KT) + 2, (BUF));                       \
                       stageHalf(1, 0, (KT) + 2, (BUF)); }                     \
    __builtin_amdgcn_s_barrier();                                              \
    LKW(0); SB0; PRI(1); MF16(1, 1, bv1) PRI(0);                               \
    /* P4: stage B1(kt+2)->buf | VMW | barrier | MFMA(1,0) */                  \
    if ((MODE) == 0) stageHalf(1, 1, (KT) + 2, (BUF));                         \
    if ((MODE) == 0) { VMW(6); } else if ((MODE) == 1) { VMW(0); }             \
    __builtin_amdgcn_s_barrier();                                              \
    SB0; PRI(1); MF16(1, 0, bv0) PRI(0);                                       \
  }

  bf16x8 af[2][4], bv0[2][2], bv1[2][2];

  // Prologue (template: vmcnt(4) after 4 halves, vmcnt(6) after +3):
  stageHalf(0, 0, 0, 0); stageHalf(1, 0, 0, 0);
  stageHalf(0, 1, 0, 0); stageHalf(1, 1, 0, 0);
  VMW(4);
  stageHalf(0, 0, 1, 1); stageHalf(1, 0, 1, 1); stageHalf(1, 1, 1, 1);
  VMW(6);
  __builtin_amdgcn_s_barrier();

  for (int kt = 0; kt < NT - 2; kt += 2) {
    KTILE(0, kt, 0)
    KTILE(1, kt + 1, 0)
  }
  KTILE(0, 62, 1)
  KTILE(1, 63, 2)

#undef KTILE
#undef MF16
#undef RD_B
#undef RD_A
#undef PRI
#undef SB0
#undef LKW
#undef VMW

  // Epilogue: D row = fq*4 + rr, col = fr (m89/m91-verified), fused bias.
#pragma unroll
  for (int nj = 0; nj < 4; ++nj) {
    const int nh = nj >> 1, j = nj & 1;
    const int col = tn + wn * 32 + nh * 128 + j * 16 + fr;
    const float bvs = bias[col];
#pragma unroll
    for (int mi = 0; mi < 8; ++mi) {
      const int mh = mi >> 2, i = mi & 3;
      const int row0 = tm + wm * 64 + mh * 128 + i * 16 + fq * 4;
#pragma unroll
      for (int rr = 0; rr < 4; ++rr)
        C[(size_t)(row0 + rr) * NOUT + col] = acc[mi][nj][rr] + bvs;
    }
  }
}

extern "C" void kernel_launch(void* const* d_in, const int* in_sizes, int n_in,
                              void* d_out, int out_size, void* d_ws, size_t ws_size,
                              hipStream_t stream) {
  const float* x    = (const float*)d_in[0];   // [8192][4096] fp32
  const float* bias = (const float*)d_in[1];   // [4096] fp32
  const int*   seed = (const int*)d_in[2];     // [1] int
  float* y = (float*)d_out;                    // [8192][4096] fp32

  // workspace: W bf16 (32 MB) | x bf16 (64 MB) — 96 MB, proven available
  uint16_t* Wb = (uint16_t*)d_ws;
  uint16_t* Xb = Wb + (size_t)NOUT * KIN;

  prep_kernel<<<65536 + 16384, 256, 0, stream>>>(x, Xb, Wb, seed);

  const int grid = (TOKENS / BM) * (NOUT / BN);   // 512
  gemm_bias_kernel<<<grid, 512, 0, stream>>>(Xb, Wb, bias, y);
}

// Round 13
// 252.033 us; speedup vs baseline: 1.3140x; 1.0831x over previous
//
#include <hip/hip_runtime.h>
#include <hip/hip_bf16.h>
#include <stdint.h>

#define TOKENS 8192
#define NOUT   4096
#define KIN    4096

#define BM 256
#define BN 256
#define BK 64
#define NT (KIN / BK)   // 64 K-tiles

typedef __attribute__((ext_vector_type(8))) short bf16x8;
typedef __attribute__((ext_vector_type(4))) float f32x4;

__device__ __forceinline__ uint32_t rotl32(uint32_t x, int r) {
  return (x << r) | (x >> (32 - r));
}

__device__ __forceinline__ uint16_t f2bf_rne(float f) {
  uint32_t u = __float_as_uint(f);
  u += 0x7FFFu + ((u >> 16) & 1u);
  return (uint16_t)(u >> 16);
}

// Threefry-2x32, 20 rounds — JAX PRNG core.
__device__ __forceinline__ void threefry2x32(uint32_t k0, uint32_t k1,
                                             uint32_t c0, uint32_t c1,
                                             uint32_t& o0, uint32_t& o1) {
  uint32_t ks2 = 0x1BD11BDAu ^ k0 ^ k1;
  uint32_t x0 = c0 + k0;
  uint32_t x1 = c1 + k1;
#define TFR(r) { x0 += x1; x1 = rotl32(x1, (r)); x1 ^= x0; }
  TFR(13) TFR(15) TFR(26) TFR(6)
  x0 += k1;  x1 += ks2 + 1u;
  TFR(17) TFR(29) TFR(16) TFR(24)
  x0 += ks2; x1 += k0 + 2u;
  TFR(13) TFR(15) TFR(26) TFR(6)
  x0 += k0;  x1 += k1 + 3u;
  TFR(17) TFR(29) TFR(16) TFR(24)
  x0 += k1;  x1 += ks2 + 4u;
  TFR(13) TFR(15) TFR(26) TFR(6)
  x0 += ks2; x1 += k0 + 5u;
#undef TFR
  o0 = x0; o1 = x1;
}

// Fused prep with INTERLEAVED roles (4 hydrate : 1 convert by b%5) so the
// VALU-bound threefry and BW-bound convert occupy CUs concurrently instead
// of dispatching serially. Hydration math VERIFIED round 3.
__global__ void prep_kernel(const float* __restrict__ x,
                            uint16_t* __restrict__ xb,
                            uint16_t* __restrict__ W,
                            const int* __restrict__ seed_ptr) {
  uint32_t b = blockIdx.x;
  uint32_t g = b / 5u, r = b % 5u;
  if (r < 4u) {
    uint32_t k1 = (uint32_t)(*seed_ptr);                  // key = (0, seed)
    uint32_t j = (g * 4u + r) * 256u + threadIdx.x;       // 0 .. 2^24-1
    uint32_t o0, o1;
    threefry2x32(0u, k1, 0u, j, o0, o1);
    uint32_t bits = o0 ^ o1;
    const float scale = 0.03125f;
    const float mn    = -0.015625f;
    float f = __uint_as_float((bits >> 9) | 0x3F800000u) - 1.0f;
    float v = fmaxf(mn, f * scale + mn);
    W[j] = f2bf_rne(v);
  } else {
    uint32_t base = (g * 256u + threadIdx.x) * 8u;
    f32x4 a = *(const f32x4*)(x + base);
    f32x4 c = *(const f32x4*)(x + base + 4);
    union { uint16_t u[8]; bf16x8 v; } rr;
    rr.u[0] = f2bf_rne(a[0]); rr.u[1] = f2bf_rne(a[1]);
    rr.u[2] = f2bf_rne(a[2]); rr.u[3] = f2bf_rne(a[3]);
    rr.u[4] = f2bf_rne(c[0]); rr.u[5] = f2bf_rne(c[1]);
    rr.u[6] = f2bf_rne(c[2]); rr.u[7] = f2bf_rne(c[3]);
    *(bf16x8*)(xb + base) = rr.v;
  }
}

// ---------------------------------------------------------------------------
// 256x256 / BK=64 / 8-wave / 16x16x32, single-barrier phases (r12) +
// SPLIT-LGKM: reads issued s0-group then s1-group (order pinned by SB0);
// after the barrier, lgkm(6/2/4) covers only the s0 group -> 8 MFMA (s0)
// run while the s1 group drains -> lgkm(0) -> 8 MFMA (s1). Hides roughly
// half of each phase's LDS drain under MFMA (r12 model: drain+MFMA were
// fully serialized; P1 drain alone ~1150 cyc/CU).
//
// Phase/stage/barrier ledger IDENTICAL to r12 (verified):
//   P1: reads A0,B0 (12) | stage A1(kt+1)->buf^1 | barrier | 16 MFMA(0,0)
//   P2: reads B1 (4)     |                       | barrier | 16 MFMA(0,1)
//   P3: reads A1 (8)     | stage A0+B0(kt+2)->buf| barrier | 16 MFMA(1,1)
//   P4: no reads         | stage B1(kt+2)+VMW(6) | barrier | 16 MFMA(1,0)
// WAR: 2-phase lag stage slots (proof in r12 comments); RAW @P4 VMW(6):
// 6 newest = P3+P4's kt+2 loads -> all of kt+1 landed. Registers: 64
// operand VGPRs (no spill). LDS swizzle: linear gload_lds dest +
// inverse-swizzled global source; reads XOR ((row&7)<<4); 0 conflicts.
// ---------------------------------------------------------------------------
__global__ __launch_bounds__(512, 2)
void gemm_bias_kernel(const uint16_t* __restrict__ A,   // x  bf16 [TOKENS][KIN]
                      const uint16_t* __restrict__ B,   // W  bf16 [NOUT][KIN]
                      const float* __restrict__ bias,
                      float* __restrict__ C) {
  __shared__ uint16_t smem[2][2][16384];   // [buf][A=0/B=1][32KB] = 128 KiB

  const int nwgn = NOUT / BN;                 // 16
  const int nwg  = (TOKENS / BM) * nwgn;      // 512 (divisible by 8)
  int bid = blockIdx.x;
  int cpx = nwg >> 3;
  int swzb = (bid & 7) * cpx + (bid >> 3);    // bijective XCD swizzle
  int tm = (swzb / nwgn) * BM;
  int tn = (swzb % nwgn) * BN;

  const int t    = threadIdx.x;
  const int lane = t & 63;
  const int wid  = t >> 6;       // 0..7
  const int wm   = wid >> 2;     // 0..1
  const int wn   = wid & 3;      // 0..3
  const int fr   = lane & 15;
  const int fq   = lane >> 4;

  const int swzRd = (lane & 7) << 4;                    // frag-read byte XOR
  const int lsw   = ((lane & 7) ^ (lane >> 3)) << 4;    // stage src byte offset

  f32x4 acc[8][4] = {};

  auto stageHalf = [&](int mat, int h, int kt, int buf) {
    const uint16_t* g = mat ? B : A;
    const int rb = (mat ? tn : tm) + h * 128 + wid * 16 + (lane >> 3);
    const char* src = (const char*)(g + (size_t)rb * KIN) + kt * 128 + lsw;
    char* dst = (char*)&smem[buf][mat][0] + h * 16384 + wid * 2048 + lane * 16;
#pragma unroll
    for (int q = 0; q < 2; ++q) {
      __builtin_amdgcn_global_load_lds(
          (const __attribute__((address_space(1))) void*)(src + (size_t)q * 8 * KIN * 2),
          (__attribute__((address_space(3))) void*)(dst + q * 1024),
          16, 0, 0);
    }
  };

#define VMW(N) asm volatile("s_waitcnt vmcnt(" #N ")" ::: "memory")
#define LKW(N) asm volatile("s_waitcnt lgkmcnt(" #N ")" ::: "memory")
#define SB0    __builtin_amdgcn_sched_barrier(0)
#define PRI(p) __builtin_amdgcn_s_setprio(p)

// 4 ds_read_b128: af[S][0..3] of half MH (one k-step group)
#define RD_AS(BUFI, MH, S)                                                     \
    _Pragma("unroll")                                                          \
    for (int i_ = 0; i_ < 4; ++i_)                                             \
      af[S][i_] = *(const bf16x8*)((const char*)&smem[BUFI][0][0] +            \
          (wm * 64 + (MH) * 128 + i_ * 16 + fr) * 128 +                        \
          ((((S) << 6) | (fq << 4)) ^ swzRd));

// 2 ds_read_b128: BV[S][0..1] of half NH
#define RD_BS(BUFI, BV, NH, S)                                                 \
    _Pragma("unroll")                                                          \
    for (int j_ = 0; j_ < 2; ++j_)                                             \
      BV[S][j_] = *(const bf16x8*)((const char*)&smem[BUFI][1][0] +            \
          (wn * 32 + (NH) * 128 + j_ * 16 + fr) * 128 +                        \
          ((((S) << 6) | (fq << 4)) ^ swzRd));

// 8 MFMA: one k-step group S of quadrant (MH,NH)
#define MF8(MH, NH, BV, S)                                                     \
    _Pragma("unroll")                                                          \
    for (int i_ = 0; i_ < 4; ++i_)                                             \
      _Pragma("unroll")                                                        \
      for (int j_ = 0; j_ < 2; ++j_)                                           \
        acc[(MH) * 4 + i_][(NH) * 2 + j_] =                                    \
            __builtin_amdgcn_mfma_f32_16x16x32_bf16(                           \
                af[S][i_], BV[S][j_], acc[(MH) * 4 + i_][(NH) * 2 + j_],       \
                0, 0, 0);

  // MODE: 0 = steady; 1 = kt62 (stage only A1(63)@P1, VMW(0)@P4);
  //       2 = kt63 (no stages, no vm waits).
#define KTILE(BUF, KT, MODE)                                                   \
  {                                                                            \
    /* P1: reads A0,B0 (s0 then s1, SB0-pinned) | stage A1(kt+1)->buf^1 */     \
    RD_AS(BUF, 0, 0) RD_BS(BUF, bv0, 0, 0)                                     \
    SB0;                                                                       \
    RD_AS(BUF, 0, 1) RD_BS(BUF, bv0, 0, 1)                                     \
    if ((MODE) <= 1) stageHalf(0, 1, (KT) + 1, (BUF) ^ 1);                     \
    __builtin_amdgcn_s_barrier();                                              \
    LKW(6); SB0; PRI(1); MF8(0, 0, bv0, 0)                                     \
    LKW(0); SB0; MF8(0, 0, bv0, 1) PRI(0);                                     \
    /* P2: reads B1 (s0 then s1) */                                            \
    RD_BS(BUF, bv1, 1, 0)                                                      \
    SB0;                                                                       \
    RD_BS(BUF, bv1, 1, 1)                                                      \
    __builtin_amdgcn_s_barrier();                                              \
    LKW(2); SB0; PRI(1); MF8(0, 1, bv1, 0)                                     \
    LKW(0); SB0; MF8(0, 1, bv1, 1) PRI(0);                                     \
    /* P3: reads A1 (s0 then s1) | stage A0+B0(kt+2)->buf */                   \
    RD_AS(BUF, 1, 0)                                                           \
    SB0;                                                                       \
    RD_AS(BUF, 1, 1)                                                           \
    if ((MODE) == 0) { stageHalf(0, 0, (KT) + 2, (BUF));                       \
                       stageHalf(1, 0, (KT) + 2, (BUF)); }                     \
    __builtin_amdgcn_s_barrier();                                              \
    LKW(4); SB0; PRI(1); MF8(1, 1, bv1, 0)                                     \
    LKW(0); SB0; MF8(1, 1, bv1, 1) PRI(0);                                     \
    /* P4: stage B1(kt+2)->buf | VMW | barrier | 16 MFMA(1,0) */               \
    if ((MODE) == 0) stageHalf(1, 1, (KT) + 2, (BUF));                         \
    if ((MODE) == 0) { VMW(6); } else if ((MODE) == 1) { VMW(0); }             \
    __builtin_amdgcn_s_barrier();                                              \
    SB0; PRI(1); MF8(1, 0, bv0, 0) MF8(1, 0, bv0, 1) PRI(0);                   \
  }

  bf16x8 af[2][4], bv0[2][2], bv1[2][2];

  // Prologue (template: vmcnt(4) after 4 halves, vmcnt(6) after +3):
  stageHalf(0, 0, 0, 0); stageHalf(1, 0, 0, 0);
  stageHalf(0, 1, 0, 0); stageHalf(1, 1, 0, 0);
  VMW(4);
  stageHalf(0, 0, 1, 1); stageHalf(1, 0, 1, 1); stageHalf(1, 1, 1, 1);
  VMW(6);
  __builtin_amdgcn_s_barrier();

  for (int kt = 0; kt < NT - 2; kt += 2) {
    KTILE(0, kt, 0)
    KTILE(1, kt + 1, 0)
  }
  KTILE(0, 62, 1)
  KTILE(1, 63, 2)

#undef KTILE
#undef MF8
#undef RD_BS
#undef RD_AS
#undef PRI
#undef SB0
#undef LKW
#undef VMW

  // Epilogue: D row = fq*4 + rr, col = fr (m89/m91-verified), fused bias.
#pragma unroll
  for (int nj = 0; nj < 4; ++nj) {
    const int nh = nj >> 1, j = nj & 1;
    const int col = tn + wn * 32 + nh * 128 + j * 16 + fr;
    const float bvs = bias[col];
#pragma unroll
    for (int mi = 0; mi < 8; ++mi) {
      const int mh = mi >> 2, i = mi & 3;
      const int row0 = tm + wm * 64 + mh * 128 + i * 16 + fq * 4;
#pragma unroll
      for (int rr = 0; rr < 4; ++rr)
        C[(size_t)(row0 + rr) * NOUT + col] = acc[mi][nj][rr] + bvs;
    }
  }
}

extern "C" void kernel_launch(void* const* d_in, const int* in_sizes, int n_in,
                              void* d_out, int out_size, void* d_ws, size_t ws_size,
                              hipStream_t stream) {
  const float* x    = (const float*)d_in[0];   // [8192][4096] fp32
  const float* bias = (const float*)d_in[1];   // [4096] fp32
  const int*   seed = (const int*)d_in[2];     // [1] int
  float* y = (float*)d_out;                    // [8192][4096] fp32

  // workspace: W bf16 (32 MB) | x bf16 (64 MB) — 96 MB, proven available
  uint16_t* Wb = (uint16_t*)d_ws;
  uint16_t* Xb = Wb + (size_t)NOUT * KIN;

  // interleaved prep: 81920 blocks, 4:1 hydrate:convert by b%5
  prep_kernel<<<81920, 256, 0, stream>>>(x, Xb, Wb, seed);

  const int grid = (TOKENS / BM) * (NOUT / BN);   // 512
  gemm_bias_kernel<<<grid, 512, 0, stream>>>(Xb, Wb, bias, y);
}